// Round 13
// baseline (31.004 us; speedup 1.0000x reference)
//
#include <hip/hip_runtime.h>

// EmbeddingBag(mean): B=1024, S=256, W=16, EMB=50, vocab=256.
// Round 13: r12 base (24.5us best) with ONE change: gather body swapped from
// the 16-level if(len>k) tree to 4 predicated GROUPS of 4 independent reads.
//  - Theory: tree = ~13.3-deep serial ds_read chain per pass (~930cy);
//    group-of-4 = <=4 epochs x 4 independent ds_read_b128 (~260cy chain).
//    Cost: ~20% more DS bytes (avg 4*ceil(len/4)=10.6 rows vs 8.5), but
//    masked lanes all read sentinel row 256 at the SAME address (broadcast).
//  - This is the one untested cell: r3 had group-of-4 w/o pipeline (26.9),
//    r6 pipeline w/ tree (24.9), r11 group-of-4 + sort whose write scatter
//    (+25MB) buried it (32.5). Clean A/B vs r12 now.
//  - Identical to r12: RSTRIDE=52, lenbuf staging, next-pass chars prefetch,
//    contiguous 512-bag chunks, coalesced float2 stores, LB(1024,8).

constexpr int EMB     = 50;
constexpr int RSTRIDE = 52;                  // dwords per row (208 B)
constexpr int ROWS    = 257;                 // 256 vocab + zero sentinel
constexpr int TBL_F   = ROWS * RSTRIDE;      // 13364 floats = 53,456 B
constexpr int NBAGS   = 1024 * 256;          // 262144
constexpr int BLOCK   = 1024;
constexpr int TPB     = 13;                  // lanes per bag (13*16B = 208B exact)
constexpr int BPP     = BLOCK / TPB;         // 78 bags per pass
constexpr int CHUNK   = 512;                 // bags per block
constexpr int NPASS   = (CHUNK + BPP - 1) / BPP;  // 7 (last pass 44 bags)
constexpr int BLOCKS  = NBAGS / CHUNK;       // 512, exact

__global__ __launch_bounds__(BLOCK, 8) void embag_r13_kernel(
    const int*   __restrict__ chars,     // [NBAGS, W=16]
    const int*   __restrict__ lengths,   // [NBAGS]
    const float* __restrict__ table,     // [256, EMB]
    float*       __restrict__ out)       // [NBAGS, EMB]
{
    __shared__ float tbl[TBL_F];
    __shared__ int   lenbuf[CHUNK];
    __shared__ float invl[17];

    const int base = blockIdx.x * CHUNK;

    // Stage table into 52-dword rows (cols 50,51 zero; row 256 all zero).
    for (int i = threadIdx.x; i < TBL_F; i += BLOCK) {
        const int r = i / RSTRIDE;
        const int c = i - r * RSTRIDE;
        tbl[i] = (r < 256 && c < EMB) ? table[r * EMB + c] : 0.0f;
    }
    if (threadIdx.x < CHUNK / 4)
        reinterpret_cast<int4*>(lenbuf)[threadIdx.x] =
            reinterpret_cast<const int4*>(lengths + base)[threadIdx.x];
    if (threadIdx.x < 17)
        invl[threadIdx.x] = threadIdx.x ? 1.0f / (float)threadIdx.x : 0.0f;
    __syncthreads();

    const int  lb     = threadIdx.x / TPB;             // bag slot in pass
    const int  t      = threadIdx.x - lb * TPB;        // float4 slot in row
    const bool active = (lb < BPP);
    const float* rowp = tbl + 4 * t;

    // Prologue: prefetch pass-0 chars (clamped; inactive lanes load bag 0).
    int idx = active ? lb : 0;
    const int4* cp = reinterpret_cast<const int4*>(chars + (size_t)(base + idx) * 16);
    int4 c0 = cp[0], c1 = cp[1], c2 = cp[2], c3 = cp[3];

    for (int p = 0; p < NPASS; ++p) {
        // Issue next pass's chars loads NOW; they retire during the gathers.
        const int idxn = (idx + BPP < CHUNK) ? idx + BPP : CHUNK - 1;
        const int4* cpn =
            reinterpret_cast<const int4*>(chars + (size_t)(base + idxn) * 16);
        const int4 n0 = cpn[0], n1 = cpn[1], n2 = cpn[2], n3 = cpn[3];

        if (active && idx < CHUNK) {
            const int len = lenbuf[idx];                // LDS, ~free

            float4 s0 = make_float4(0.f,0.f,0.f,0.f);
            float4 s1 = s0, s2 = s0, s3 = s0;

            // One group: 4 predicated INDEPENDENT ds_read_b128 + adds.
            // Masked lanes read sentinel row 256 at one address (broadcast).
            #define G4(c, wb)                                                  \
                {                                                              \
                    const int e0 = ((wb)+0 < len) ? (c).x : 256;               \
                    const int e1 = ((wb)+1 < len) ? (c).y : 256;               \
                    const int e2 = ((wb)+2 < len) ? (c).z : 256;               \
                    const int e3 = ((wb)+3 < len) ? (c).w : 256;               \
                    const float4 v0 = *reinterpret_cast<const float4*>(rowp + e0 * RSTRIDE); \
                    const float4 v1 = *reinterpret_cast<const float4*>(rowp + e1 * RSTRIDE); \
                    const float4 v2 = *reinterpret_cast<const float4*>(rowp + e2 * RSTRIDE); \
                    const float4 v3 = *reinterpret_cast<const float4*>(rowp + e3 * RSTRIDE); \
                    s0.x += v0.x; s0.y += v0.y; s0.z += v0.z; s0.w += v0.w;    \
                    s1.x += v1.x; s1.y += v1.y; s1.z += v1.z; s1.w += v1.w;    \
                    s2.x += v2.x; s2.y += v2.y; s2.z += v2.z; s2.w += v2.w;    \
                    s3.x += v3.x; s3.y += v3.y; s3.z += v3.z; s3.w += v3.w;    \
                }

            G4(c0, 0)
            if (len > 4) {
                G4(c1, 4)
                if (len > 8) {
                    G4(c2, 8)
                    if (len > 12) {
                        G4(c3, 12)
                    }
                }
            }
            #undef G4

            const float inv = invl[len];
            const float rx = ((s0.x + s1.x) + (s2.x + s3.x)) * inv;
            const float ry = ((s0.y + s1.y) + (s2.y + s3.y)) * inv;
            const float rz = ((s0.z + s1.z) + (s2.z + s3.z)) * inv;
            const float rw = ((s0.w + s1.w) + (s2.w + s3.w)) * inv;

            float* ob = out + (size_t)(base + idx) * EMB + 4u * (unsigned)t;
            reinterpret_cast<float2*>(ob)[0] = make_float2(rx, ry);
            if (t < 12)
                reinterpret_cast<float2*>(ob)[1] = make_float2(rz, rw);
        }

        c0 = n0; c1 = n1; c2 = n2; c3 = n3;
        idx += BPP;
    }
}

extern "C" void kernel_launch(void* const* d_in, const int* in_sizes, int n_in,
                              void* d_out, int out_size, void* d_ws, size_t ws_size,
                              hipStream_t stream) {
    const int*   chars   = (const int*)d_in[0];   // [B,S,W] int32
    const int*   lengths = (const int*)d_in[1];   // [B,S]   int32
    const float* table   = (const float*)d_in[2]; // [256,50] f32
    float*       out     = (float*)d_out;         // [B,S,50] f32

    embag_r13_kernel<<<dim3(BLOCKS), dim3(BLOCK), 0, stream>>>(
        chars, lengths, table, out);
}

// Round 14
// 25.017 us; speedup vs baseline: 1.2393x; 1.2393x over previous
//
#include <hip/hip_runtime.h>

// EmbeddingBag(mean): B=1024, S=256, W=16, EMB=50, vocab=256.
// Round 14: r12 base (24.5us best) with two serial-chain reductions:
//  1) PAIR-tree: 8 branch epochs (len>2k) x 2 independent ds_read_b128,
//     sentinel row only for the odd element of a live pair (~0.5 sentinel
//     rows/bag, +6% DS bytes -- unlike r13's +25% which lost).
//  2) v_pk_add_f32 / v_pk_mul_f32 (CDNA4 packed dual-f32): accumulate issue
//     halves (2 pk per row vs 4 adds); epilogue scale packed too.
//  Everything else identical to r12: RSTRIDE=52, lenbuf staging, next-pass
//  chars prefetch, 512-bag chunks, coalesced float2 stores, LB(1024,8).
// Evidence base: tree >> predicated-flat (r8/r13); pipeline+byte-trim are
// the only wins (r6/r12). This shrinks branch+add issue in the same frame.

constexpr int EMB     = 50;
constexpr int RSTRIDE = 52;                  // dwords per row (208 B)
constexpr int ROWS    = 257;                 // 256 vocab + zero sentinel
constexpr int TBL_F   = ROWS * RSTRIDE;      // 13364 floats
constexpr int NBAGS   = 1024 * 256;          // 262144
constexpr int BLOCK   = 1024;
constexpr int TPB     = 13;                  // lanes per bag (13*16B = 208B)
constexpr int BPP     = BLOCK / TPB;         // 78 bags per pass
constexpr int CHUNK   = 512;                 // bags per block
constexpr int NPASS   = (CHUNK + BPP - 1) / BPP;  // 7
constexpr int BLOCKS  = NBAGS / CHUNK;       // 512, exact

typedef __attribute__((ext_vector_type(2))) float f32x2;

__device__ __forceinline__ f32x2 pk_add(f32x2 a, f32x2 b) {
    f32x2 d;
    asm("v_pk_add_f32 %0, %1, %2" : "=v"(d) : "v"(a), "v"(b));
    return d;
}
__device__ __forceinline__ f32x2 pk_mul(f32x2 a, f32x2 b) {
    f32x2 d;
    asm("v_pk_mul_f32 %0, %1, %2" : "=v"(d) : "v"(a), "v"(b));
    return d;
}

__global__ __launch_bounds__(BLOCK, 8) void embag_r14_kernel(
    const int*   __restrict__ chars,     // [NBAGS, W=16]
    const int*   __restrict__ lengths,   // [NBAGS]
    const float* __restrict__ table,     // [256, EMB]
    float*       __restrict__ out)       // [NBAGS, EMB]
{
    __shared__ float tbl[TBL_F];
    __shared__ int   lenbuf[CHUNK];
    __shared__ float invl[17];

    const int base = blockIdx.x * CHUNK;

    // Stage table into 52-dword rows (cols 50,51 zero; row 256 all zero).
    for (int i = threadIdx.x; i < TBL_F; i += BLOCK) {
        const int r = i / RSTRIDE;
        const int c = i - r * RSTRIDE;
        tbl[i] = (r < 256 && c < EMB) ? table[r * EMB + c] : 0.0f;
    }
    if (threadIdx.x < CHUNK / 4)
        reinterpret_cast<int4*>(lenbuf)[threadIdx.x] =
            reinterpret_cast<const int4*>(lengths + base)[threadIdx.x];
    if (threadIdx.x < 17)
        invl[threadIdx.x] = threadIdx.x ? 1.0f / (float)threadIdx.x : 0.0f;
    __syncthreads();

    const int  lb     = threadIdx.x / TPB;             // bag slot in pass
    const int  t      = threadIdx.x - lb * TPB;        // float4 slot in row
    const bool active = (lb < BPP);
    const float* rowp = tbl + 4 * t;

    // Prologue: prefetch pass-0 chars (clamped; inactive lanes load bag 0).
    int idx = active ? lb : 0;
    const int4* cp = reinterpret_cast<const int4*>(chars + (size_t)(base + idx) * 16);
    int4 c0 = cp[0], c1 = cp[1], c2 = cp[2], c3 = cp[3];

    for (int p = 0; p < NPASS; ++p) {
        // Issue next pass's chars loads NOW; retire under the gathers.
        const int idxn = (idx + BPP < CHUNK) ? idx + BPP : CHUNK - 1;
        const int4* cpn =
            reinterpret_cast<const int4*>(chars + (size_t)(base + idxn) * 16);
        const int4 n0 = cpn[0], n1 = cpn[1], n2 = cpn[2], n3 = cpn[3];

        if (active && idx < CHUNK) {
            const int len = lenbuf[idx];                // LDS, ~free

            f32x2 a0l = {0.f, 0.f}, a0h = {0.f, 0.f};  // even-row chains
            f32x2 a1l = {0.f, 0.f}, a1h = {0.f, 0.f};  // odd-row chains

            // One pair-level: row wb always live (guarded by enclosing
            // branch); row wb+1 -> sentinel 256 if past len. Two independent
            // ds_read_b128 per epoch, packed dual-f32 accumulate.
            #define PR(ca, cb, wb)                                             \
                {                                                              \
                    const int e1 = ((wb) + 1 < len) ? (cb) : 256;              \
                    const float4 v0 =                                          \
                        *reinterpret_cast<const float4*>(rowp + (ca) * RSTRIDE); \
                    const float4 v1 =                                          \
                        *reinterpret_cast<const float4*>(rowp + e1 * RSTRIDE); \
                    a0l = pk_add(a0l, f32x2{v0.x, v0.y});                      \
                    a0h = pk_add(a0h, f32x2{v0.z, v0.w});                      \
                    a1l = pk_add(a1l, f32x2{v1.x, v1.y});                      \
                    a1h = pk_add(a1h, f32x2{v1.z, v1.w});                      \
                }

            PR(c0.x, c0.y, 0)
            if (len > 2)  { PR(c0.z, c0.w, 2)
            if (len > 4)  { PR(c1.x, c1.y, 4)
            if (len > 6)  { PR(c1.z, c1.w, 6)
            if (len > 8)  { PR(c2.x, c2.y, 8)
            if (len > 10) { PR(c2.z, c2.w, 10)
            if (len > 12) { PR(c3.x, c3.y, 12)
            if (len > 14) { PR(c3.z, c3.w, 14) }}}}}}}
            #undef PR

            const float inv = invl[len];
            const f32x2 iv = {inv, inv};
            const f32x2 lo = pk_mul(pk_add(a0l, a1l), iv);
            const f32x2 hi = pk_mul(pk_add(a0h, a1h), iv);

            float* ob = out + (size_t)(base + idx) * EMB + 4u * (unsigned)t;
            reinterpret_cast<float2*>(ob)[0] = make_float2(lo.x, lo.y);
            if (t < 12)
                reinterpret_cast<float2*>(ob)[1] = make_float2(hi.x, hi.y);
        }

        c0 = n0; c1 = n1; c2 = n2; c3 = n3;
        idx += BPP;
    }
}

extern "C" void kernel_launch(void* const* d_in, const int* in_sizes, int n_in,
                              void* d_out, int out_size, void* d_ws, size_t ws_size,
                              hipStream_t stream) {
    const int*   chars   = (const int*)d_in[0];   // [B,S,W] int32
    const int*   lengths = (const int*)d_in[1];   // [B,S]   int32
    const float* table   = (const float*)d_in[2]; // [256,50] f32
    float*       out     = (float*)d_out;         // [B,S,50] f32

    embag_r14_kernel<<<dim3(BLOCKS), dim3(BLOCK), 0, stream>>>(
        chars, lengths, table, out);
}

// Round 15
// 24.441 us; speedup vs baseline: 1.2685x; 1.0236x over previous
//
#include <hip/hip_runtime.h>

// EmbeddingBag(mean): B=1024, S=256, W=16, EMB=50, vocab=256.
// Round 15: r12 (24.5us best) with ONE isolated change: packed f32 math.
//  - v_pk_add_f32 accumulate (2 instrs/row vs 4) + v_pk_mul_f32 epilogue.
//  - r14 bundled this with pair-level sentinel reads (+6% DS bytes,
//    +cndmask/level) and landed neutral (25.0); this isolates the pk half
//    on the EXACT winning structure: 16-level exec-mask tree (no sentinel,
//    masked lanes pay zero bank bandwidth), RSTRIDE=52, lenbuf staging,
//    next-pass chars prefetch, 512-bag chunks, coalesced float2 stores.
//  - Accumulation order per component is unchanged (same single chain,
//    adds merely packed pairwise across components) -> absmax 0 expected.

constexpr int EMB     = 50;
constexpr int RSTRIDE = 52;                  // dwords per row (208 B)
constexpr int TBL_F   = 256 * RSTRIDE;       // 13312 floats = 53,248 B
constexpr int NBAGS   = 1024 * 256;          // 262144
constexpr int BLOCK   = 1024;
constexpr int TPB     = 13;                  // lanes per bag (13*16B = 208B)
constexpr int BPP     = BLOCK / TPB;         // 78 bags per pass
constexpr int CHUNK   = 512;                 // bags per block
constexpr int NPASS   = (CHUNK + BPP - 1) / BPP;  // 7
constexpr int BLOCKS  = NBAGS / CHUNK;       // 512, exact

typedef __attribute__((ext_vector_type(2))) float f32x2;

__device__ __forceinline__ f32x2 pk_add(f32x2 a, f32x2 b) {
    f32x2 d;
    asm("v_pk_add_f32 %0, %1, %2" : "=v"(d) : "v"(a), "v"(b));
    return d;
}
__device__ __forceinline__ f32x2 pk_mul(f32x2 a, f32x2 b) {
    f32x2 d;
    asm("v_pk_mul_f32 %0, %1, %2" : "=v"(d) : "v"(a), "v"(b));
    return d;
}

__global__ __launch_bounds__(BLOCK, 8) void embag_r15_kernel(
    const int*   __restrict__ chars,     // [NBAGS, W=16]
    const int*   __restrict__ lengths,   // [NBAGS]
    const float* __restrict__ table,     // [256, EMB]
    float*       __restrict__ out)       // [NBAGS, EMB]
{
    __shared__ float tbl[TBL_F];
    __shared__ int   lenbuf[CHUNK];
    __shared__ float invl[17];

    const int base = blockIdx.x * CHUNK;

    // Stage table into 52-dword rows (cols 50,51 zero).
    for (int i = threadIdx.x; i < TBL_F; i += BLOCK) {
        const int r = i / RSTRIDE;
        const int c = i - r * RSTRIDE;
        tbl[i] = (c < EMB) ? table[r * EMB + c] : 0.0f;
    }
    if (threadIdx.x < CHUNK / 4)
        reinterpret_cast<int4*>(lenbuf)[threadIdx.x] =
            reinterpret_cast<const int4*>(lengths + base)[threadIdx.x];
    if (threadIdx.x < 17)
        invl[threadIdx.x] = threadIdx.x ? 1.0f / (float)threadIdx.x : 0.0f;
    __syncthreads();

    const int  lb     = threadIdx.x / TPB;             // bag slot in pass
    const int  t      = threadIdx.x - lb * TPB;        // float4 slot in row
    const bool active = (lb < BPP);
    const float* rowp = tbl + 4 * t;

    // Prologue: prefetch pass-0 chars (clamped; inactive lanes load bag 0).
    int idx = active ? lb : 0;
    const int4* cp = reinterpret_cast<const int4*>(chars + (size_t)(base + idx) * 16);
    int4 c0 = cp[0], c1 = cp[1], c2 = cp[2], c3 = cp[3];

    for (int p = 0; p < NPASS; ++p) {
        // Issue next pass's chars loads NOW; they retire during the gathers.
        const int idxn = (idx + BPP < CHUNK) ? idx + BPP : CHUNK - 1;
        const int4* cpn =
            reinterpret_cast<const int4*>(chars + (size_t)(base + idxn) * 16);
        const int4 n0 = cpn[0], n1 = cpn[1], n2 = cpn[2], n3 = cpn[3];

        if (active && idx < CHUNK) {
            const int len = lenbuf[idx];                // LDS, ~free

            f32x2 al = {0.f, 0.f};                     // components x,y
            f32x2 ah = {0.f, 0.f};                     // components z,w

            #define G(comp)                                                        \
                {                                                                  \
                    const float4 v =                                               \
                        *reinterpret_cast<const float4*>(rowp + (comp) * RSTRIDE); \
                    al = pk_add(al, f32x2{v.x, v.y});                              \
                    ah = pk_add(ah, f32x2{v.z, v.w});                              \
                }
            G(c0.x)
            if (len > 1)  { G(c0.y)
            if (len > 2)  { G(c0.z)
            if (len > 3)  { G(c0.w)
            if (len > 4)  { G(c1.x)
            if (len > 5)  { G(c1.y)
            if (len > 6)  { G(c1.z)
            if (len > 7)  { G(c1.w)
            if (len > 8)  { G(c2.x)
            if (len > 9)  { G(c2.y)
            if (len > 10) { G(c2.z)
            if (len > 11) { G(c2.w)
            if (len > 12) { G(c3.x)
            if (len > 13) { G(c3.y)
            if (len > 14) { G(c3.z)
            if (len > 15) { G(c3.w) }}}}}}}}}}}}}}}
            #undef G

            const float inv = invl[len];
            const f32x2 iv = {inv, inv};
            const f32x2 lo = pk_mul(al, iv);
            const f32x2 hi = pk_mul(ah, iv);

            float* ob = out + (size_t)(base + idx) * EMB + 4u * (unsigned)t;
            reinterpret_cast<float2*>(ob)[0] = make_float2(lo.x, lo.y);
            if (t < 12)
                reinterpret_cast<float2*>(ob)[1] = make_float2(hi.x, hi.y);
        }

        c0 = n0; c1 = n1; c2 = n2; c3 = n3;
        idx += BPP;
    }
}

extern "C" void kernel_launch(void* const* d_in, const int* in_sizes, int n_in,
                              void* d_out, int out_size, void* d_ws, size_t ws_size,
                              hipStream_t stream) {
    const int*   chars   = (const int*)d_in[0];   // [B,S,W] int32
    const int*   lengths = (const int*)d_in[1];   // [B,S]   int32
    const float* table   = (const float*)d_in[2]; // [256,50] f32
    float*       out     = (float*)d_out;         // [B,S,50] f32

    embag_r15_kernel<<<dim3(BLOCKS), dim3(BLOCK), 0, stream>>>(
        chars, lengths, table, out);
}